// Round 11
// baseline (255.587 us; speedup 1.0000x reference)
//
#include <hip/hip_runtime.h>
#include <hip/hip_bf16.h>

#define LN_EPS 1e-5f
#define BSH   7                  // bucket shift: 128 nodes/bucket
#define BNODE 128
#define EPB   8192               // edges per bucket_scatter block
#define CAP   4096               // max edges per bucket stageable in LDS

// ---------------- CSR prefix build (deg + rowstart) ----------------

__global__ __launch_bounds__(256) void hist_kernel(
    const int* __restrict__ ei, int* __restrict__ deg, int E)
{
    int e = blockIdx.x * 256 + threadIdx.x;
    if (e < E) atomicAdd(&deg[ei[E + e]], 1);
}

__global__ __launch_bounds__(256) void scan1_kernel(
    const int* __restrict__ deg, int* __restrict__ rowstart,
    int* __restrict__ tilesum, int n)
{
    __shared__ int wsum[4];
    int t = threadIdx.x;
    int base = blockIdx.x * 2048 + t * 8;
    int v[8]; int tsum = 0;
    #pragma unroll
    for (int i = 0; i < 8; ++i) { v[i] = (base + i < n) ? deg[base + i] : 0; tsum += v[i]; }
    int lane = t & 63, w = t >> 6;
    int sc = tsum;
    #pragma unroll
    for (int off = 1; off < 64; off <<= 1) {
        int y = __shfl_up(sc, off);
        if (lane >= off) sc += y;
    }
    if (lane == 63) wsum[w] = sc;
    __syncthreads();
    int woff = 0;
    for (int j = 0; j < w; ++j) woff += wsum[j];
    int run = woff + sc - tsum;
    #pragma unroll
    for (int i = 0; i < 8; ++i) { if (base + i < n) rowstart[base + i] = run; run += v[i]; }
    if (t == 255) tilesum[blockIdx.x] = wsum[0] + wsum[1] + wsum[2] + wsum[3];
}

__global__ void scan2_kernel(int* tilesum, int T)
{
    if (blockIdx.x == 0 && threadIdx.x == 0) {
        int run = 0;
        for (int i = 0; i < T; ++i) { int v = tilesum[i]; tilesum[i] = run; run += v; }
    }
}

// also seeds gcursor[b] = rowstart[b*128]
__global__ __launch_bounds__(256) void scan3_kernel(
    int* __restrict__ rowstart, const int* __restrict__ tilesum,
    int* __restrict__ gcursor, int n, int E)
{
    int i = blockIdx.x * 256 + threadIdx.x;
    if (i < n) {
        int v = rowstart[i] + tilesum[i >> 11];
        rowstart[i] = v;
        if ((i & (BNODE - 1)) == 0) gcursor[i >> BSH] = v;
    }
    if (i == 0) rowstart[n] = E;
}

// ---------------- bucket scatter ----------------
__global__ __launch_bounds__(256) void bucket_scatter_kernel(
    const int* __restrict__ ei,
    int* __restrict__ gcursor,
    int* __restrict__ ebuf,
    int E, int NB)
{
    __shared__ int lhist[1024];   // NB = 782 for N = 100k
    __shared__ int lbase[1024];
    __shared__ int lcur[1024];

    int t = threadIdx.x;
    int base = blockIdx.x * EPB;

    for (int b = t; b < NB; b += 256) lhist[b] = 0;
    __syncthreads();

    #pragma unroll 4
    for (int i = 0; i < EPB / 256; ++i) {
        int e = base + i * 256 + t;          // coalesced
        if (e < E) atomicAdd(&lhist[ei[E + e] >> BSH], 1);
    }
    __syncthreads();

    for (int b = t; b < NB; b += 256) {
        int c = lhist[b];
        lbase[b] = c ? atomicAdd(&gcursor[b], c) : 0;
        lcur[b]  = 0;
    }
    __syncthreads();

    #pragma unroll 4
    for (int i = 0; i < EPB / 256; ++i) {
        int e = base + i * 256 + t;
        if (e < E) {
            int src = ei[e];
            int dst = ei[E + e];
            int b   = dst >> BSH;
            int pos = lbase[b] + atomicAdd(&lcur[b], 1);
            ebuf[pos] = src | ((dst & (BNODE - 1)) << 17);
        }
    }
}

// ---------------- csrsort: bucket -> exact CSR order via LDS ----------------
__global__ __launch_bounds__(256) void csrsort_kernel(
    const int* __restrict__ rowstart,
    const int* __restrict__ ebuf,
    int* __restrict__ esrc,
    int N)
{
    __shared__ int rbase[BNODE + 1];
    __shared__ int lcur[BNODE];
    __shared__ int sorted[CAP];

    int t    = threadIdx.x;
    int nb0  = blockIdx.x << BSH;
    int top  = min(nb0 + BNODE, N);
    int nloc = top - nb0;

    for (int i = t; i <= nloc; i += 256) rbase[i] = rowstart[nb0 + i];
    for (int i = t; i < nloc;  i += 256) lcur[i] = 0;
    __syncthreads();

    int s0 = rbase[0], s1 = rbase[nloc];
    int cnt = s1 - s0;

    if (cnt <= CAP) {
        for (int i = s0 + t; i < s1; i += 256) {
            int p = ebuf[i];
            int n = p >> 17;
            int slot = (rbase[n] - s0) + atomicAdd(&lcur[n], 1);
            sorted[slot] = p & 0x1FFFF;
        }
        __syncthreads();
        for (int i = t; i < cnt; i += 256) esrc[s0 + i] = sorted[i];  // coalesced
    } else {
        for (int i = s0 + t; i < s1; i += 256) {
            int p = ebuf[i];
            int n = p >> 17;
            int slot = rbase[n] + atomicAdd(&lcur[n], 1);
            esrc[slot] = p & 0x1FFFF;
        }
    }
}

// ---------------- gather: CSR mean-aggregate (round-3 proven) ----------------
__global__ __launch_bounds__(256) void gather_kernel(
    const float* __restrict__ x,
    const int*   __restrict__ rowstart,
    const int*   __restrict__ esrc,
    float* __restrict__ mean,
    int N)
{
    int tid  = threadIdx.x;
    int lane = tid & 63;
    int g    = lane >> 4;
    int l4   = (lane & 15) * 4;
    int node = blockIdx.x * 4 + (tid >> 6);
    if (node >= N) return;
    int s0 = rowstart[node], s1 = rowstart[node + 1];

    float4 a0 = make_float4(0.f, 0.f, 0.f, 0.f);
    float4 a1 = make_float4(0.f, 0.f, 0.f, 0.f);
    int e = s0 + g;
    for (; e + 4 < s1; e += 8) {
        int sA = esrc[e];
        int sB = esrc[e + 4];
        float4 va = *(const float4*)&x[(size_t)sA * 64 + l4];
        float4 vb = *(const float4*)&x[(size_t)sB * 64 + l4];
        a0.x += va.x; a0.y += va.y; a0.z += va.z; a0.w += va.w;
        a1.x += vb.x; a1.y += vb.y; a1.z += vb.z; a1.w += vb.w;
    }
    if (e < s1) {
        float4 va = *(const float4*)&x[(size_t)esrc[e] * 64 + l4];
        a0.x += va.x; a0.y += va.y; a0.z += va.z; a0.w += va.w;
    }
    a0.x += a1.x; a0.y += a1.y; a0.z += a1.z; a0.w += a1.w;

    a0.x += __shfl_xor(a0.x, 32); a0.y += __shfl_xor(a0.y, 32);
    a0.z += __shfl_xor(a0.z, 32); a0.w += __shfl_xor(a0.w, 32);
    a0.x += __shfl_xor(a0.x, 16); a0.y += __shfl_xor(a0.y, 16);
    a0.z += __shfl_xor(a0.z, 16); a0.w += __shfl_xor(a0.w, 16);

    if (g == 0) {
        float inv = 1.0f / fmaxf((float)(s1 - s0), 1.0f);
        float4 r = make_float4(a0.x * inv, a0.y * inv, a0.z * inv, a0.w * inv);
        *(float4*)&mean[(size_t)node * 64 + l4] = r;
    }
}

// ---------------- MLP + LayerNorm + ELU ----------------
// Round-10 structure (thread=node, wave=j-quarter, s_load weights via
// readfirstlane'd `part`), with the c-loop FULLY UNROLLED: round 10's rolled
// loop (VGPR=24) serialized {4 VMEM loads -> wait -> 512 fmac cyc} per chunk,
// exposing ~400cyc of VMEM latency 8x per thread (VALUBusy 36%, dur 48us).
// Unrolling makes all 32 input loads independent so the compiler hoists load
// batches ahead of the fmac stream; VGPR headroom (128 @ 4 waves/EU) is ample.
__global__ __launch_bounds__(256, 4) void mlp_kernel(
    const float* __restrict__ x,
    const float* mean,              // aliases out - no restrict
    const float* __restrict__ Wl,
    const float* __restrict__ Wr,
    const float* __restrict__ bias,
    const float* __restrict__ gamma,
    const float* __restrict__ beta,
    float* out,
    int N)
{
    __shared__ float sp[4][64];
    __shared__ float sq[4][64];

    int lane = threadIdx.x & 63;
    int part = __builtin_amdgcn_readfirstlane(threadIdx.x >> 6); // SGPR-pinned
    int nbase = blockIdx.x * 64;
    int node  = nbase + lane;
    bool act  = node < N;
    size_t row = (size_t)(act ? node : 0) * 64;

    const float* Wlp = Wl + part * 16 * 64;   // provably uniform -> s_load
    const float* Wrp = Wr + part * 16 * 64;

    float acc[16];
    #pragma unroll
    for (int j = 0; j < 16; ++j) acc[j] = bias[part * 16 + j];

    #pragma unroll
    for (int c = 0; c < 8; ++c) {
        float4 ma = *(const float4*)&mean[row + c * 8];
        float4 mb = *(const float4*)&mean[row + c * 8 + 4];
        float4 xa = *(const float4*)&x[row + c * 8];
        float4 xb = *(const float4*)&x[row + c * 8 + 4];
        float vm[8] = {ma.x, ma.y, ma.z, ma.w, mb.x, mb.y, mb.z, mb.w};
        float vx[8] = {xa.x, xa.y, xa.z, xa.w, xb.x, xb.y, xb.z, xb.w};
        const float* wlc = Wlp + c * 8;
        const float* wrc = Wrp + c * 8;
        #pragma unroll
        for (int j = 0; j < 16; ++j) {
            #pragma unroll
            for (int d = 0; d < 8; ++d) {
                acc[j] += wlc[j * 64 + d] * vm[d]
                        + wrc[j * 64 + d] * vx[d];
            }
        }
    }

    float s0 = 0.f, s1 = 0.f, q0 = 0.f, q1 = 0.f;
    #pragma unroll
    for (int j = 0; j < 8; ++j) {
        s0 += acc[j];     q0 += acc[j] * acc[j];
        s1 += acc[j + 8]; q1 += acc[j + 8] * acc[j + 8];
    }
    sp[part][lane] = s0 + s1;
    sq[part][lane] = q0 + q1;
    __syncthreads();

    float st = (sp[0][lane] + sp[1][lane]) + (sp[2][lane] + sp[3][lane]);
    float qt = (sq[0][lane] + sq[1][lane]) + (sq[2][lane] + sq[3][lane]);
    float mu  = st * (1.0f / 64.0f);
    float var = qt * (1.0f / 64.0f) - mu * mu;
    float r   = rsqrtf(var + LN_EPS);

    if (act) {
        #pragma unroll
        for (int cc = 0; cc < 4; ++cc) {
            float4 g4 = *(const float4*)&gamma[part * 16 + cc * 4];
            float4 b4 = *(const float4*)&beta[part * 16 + cc * 4];
            float4 o;
            o.x = (acc[cc*4+0] - mu) * r * g4.x + b4.x;
            o.y = (acc[cc*4+1] - mu) * r * g4.y + b4.y;
            o.z = (acc[cc*4+2] - mu) * r * g4.z + b4.z;
            o.w = (acc[cc*4+3] - mu) * r * g4.w + b4.w;
            o.x = o.x > 0.f ? o.x : __expf(o.x) - 1.0f;
            o.y = o.y > 0.f ? o.y : __expf(o.y) - 1.0f;
            o.z = o.z > 0.f ? o.z : __expf(o.z) - 1.0f;
            o.w = o.w > 0.f ? o.w : __expf(o.w) - 1.0f;
            *(float4*)&out[(size_t)node * 64 + part * 16 + cc * 4] = o;
        }
    }
}

extern "C" void kernel_launch(void* const* d_in, const int* in_sizes, int n_in,
                              void* d_out, int out_size, void* d_ws, size_t ws_size,
                              hipStream_t stream) {
    const float* x     = (const float*)d_in[0];
    const int*   ei    = (const int*)  d_in[1];
    const float* Wl    = (const float*)d_in[2];
    const float* Wr    = (const float*)d_in[3];
    const float* bias  = (const float*)d_in[4];
    const float* gamma = (const float*)d_in[5];
    const float* beta  = (const float*)d_in[6];

    int N  = in_sizes[0] / 64;
    int E  = in_sizes[1] / 2;
    int NB = (N + BNODE - 1) >> BSH;       // 782 buckets

    int* deg      = (int*)d_ws;            // N
    int* rowstart = deg + N;               // N+1
    int* tilesum  = rowstart + (N + 1);    // <=64
    int* gcursor  = tilesum + 64;          // NB
    int* ebuf     = gcursor + NB;          // E (packed src | dstlocal<<17)
    int* esrc     = ebuf + E;              // E (CSR-ordered src)
    float* mean   = (float*)d_out;         // N*64; mlp reads its rows pre-barrier

    hipMemsetAsync(deg, 0, (size_t)N * sizeof(int), stream);

    hist_kernel<<<(E + 255) / 256, 256, 0, stream>>>(ei, deg, E);

    int T = (N + 2047) / 2048;
    scan1_kernel<<<T, 256, 0, stream>>>(deg, rowstart, tilesum, N);
    scan2_kernel<<<1, 64, 0, stream>>>(tilesum, T);
    scan3_kernel<<<(N + 255) / 256, 256, 0, stream>>>(rowstart, tilesum, gcursor, N, E);

    bucket_scatter_kernel<<<(E + EPB - 1) / EPB, 256, 0, stream>>>(ei, gcursor,
                                                                   ebuf, E, NB);

    csrsort_kernel<<<NB, 256, 0, stream>>>(rowstart, ebuf, esrc, N);

    gather_kernel<<<(N + 3) / 4, 256, 0, stream>>>(x, rowstart, esrc, mean, N);

    mlp_kernel<<<(N + 63) / 64, 256, 0, stream>>>(x, mean, Wl, Wr, bias, gamma, beta,
                                                  (float*)d_out, N);
}

// Round 12
// 174.764 us; speedup vs baseline: 1.4625x; 1.4625x over previous
//
#include <hip/hip_runtime.h>
#include <hip/hip_bf16.h>

#define LN_EPS 1e-5f
#define BSH   7                  // bucket shift: 128 nodes/bucket
#define BNODE 128
#define EPB   8192               // edges per bucket_scatter block
#define CAP   4096               // max edges per bucket stageable in LDS

// ---------------- CSR prefix build (deg + rowstart) ----------------

__global__ __launch_bounds__(256) void hist_kernel(
    const int* __restrict__ ei, int* __restrict__ deg, int E)
{
    int e = blockIdx.x * 256 + threadIdx.x;
    if (e < E) atomicAdd(&deg[ei[E + e]], 1);
}

__global__ __launch_bounds__(256) void scan1_kernel(
    const int* __restrict__ deg, int* __restrict__ rowstart,
    int* __restrict__ tilesum, int n)
{
    __shared__ int wsum[4];
    int t = threadIdx.x;
    int base = blockIdx.x * 2048 + t * 8;
    int v[8]; int tsum = 0;
    #pragma unroll
    for (int i = 0; i < 8; ++i) { v[i] = (base + i < n) ? deg[base + i] : 0; tsum += v[i]; }
    int lane = t & 63, w = t >> 6;
    int sc = tsum;
    #pragma unroll
    for (int off = 1; off < 64; off <<= 1) {
        int y = __shfl_up(sc, off);
        if (lane >= off) sc += y;
    }
    if (lane == 63) wsum[w] = sc;
    __syncthreads();
    int woff = 0;
    for (int j = 0; j < w; ++j) woff += wsum[j];
    int run = woff + sc - tsum;
    #pragma unroll
    for (int i = 0; i < 8; ++i) { if (base + i < n) rowstart[base + i] = run; run += v[i]; }
    if (t == 255) tilesum[blockIdx.x] = wsum[0] + wsum[1] + wsum[2] + wsum[3];
}

__global__ void scan2_kernel(int* tilesum, int T)
{
    if (blockIdx.x == 0 && threadIdx.x == 0) {
        int run = 0;
        for (int i = 0; i < T; ++i) { int v = tilesum[i]; tilesum[i] = run; run += v; }
    }
}

// also seeds gcursor[b] = rowstart[b*128]
__global__ __launch_bounds__(256) void scan3_kernel(
    int* __restrict__ rowstart, const int* __restrict__ tilesum,
    int* __restrict__ gcursor, int n, int E)
{
    int i = blockIdx.x * 256 + threadIdx.x;
    if (i < n) {
        int v = rowstart[i] + tilesum[i >> 11];
        rowstart[i] = v;
        if ((i & (BNODE - 1)) == 0) gcursor[i >> BSH] = v;
    }
    if (i == 0) rowstart[n] = E;
}

// ---------------- bucket scatter ----------------
__global__ __launch_bounds__(256) void bucket_scatter_kernel(
    const int* __restrict__ ei,
    int* __restrict__ gcursor,
    int* __restrict__ ebuf,
    int E, int NB)
{
    __shared__ int lhist[1024];   // NB = 782 for N = 100k
    __shared__ int lbase[1024];
    __shared__ int lcur[1024];

    int t = threadIdx.x;
    int base = blockIdx.x * EPB;

    for (int b = t; b < NB; b += 256) lhist[b] = 0;
    __syncthreads();

    #pragma unroll 4
    for (int i = 0; i < EPB / 256; ++i) {
        int e = base + i * 256 + t;          // coalesced
        if (e < E) atomicAdd(&lhist[ei[E + e] >> BSH], 1);
    }
    __syncthreads();

    for (int b = t; b < NB; b += 256) {
        int c = lhist[b];
        lbase[b] = c ? atomicAdd(&gcursor[b], c) : 0;
        lcur[b]  = 0;
    }
    __syncthreads();

    #pragma unroll 4
    for (int i = 0; i < EPB / 256; ++i) {
        int e = base + i * 256 + t;
        if (e < E) {
            int src = ei[e];
            int dst = ei[E + e];
            int b   = dst >> BSH;
            int pos = lbase[b] + atomicAdd(&lcur[b], 1);
            ebuf[pos] = src | ((dst & (BNODE - 1)) << 17);
        }
    }
}

// ---------------- csrsort: bucket -> exact CSR order via LDS ----------------
__global__ __launch_bounds__(256) void csrsort_kernel(
    const int* __restrict__ rowstart,
    const int* __restrict__ ebuf,
    int* __restrict__ esrc,
    int N)
{
    __shared__ int rbase[BNODE + 1];
    __shared__ int lcur[BNODE];
    __shared__ int sorted[CAP];

    int t    = threadIdx.x;
    int nb0  = blockIdx.x << BSH;
    int top  = min(nb0 + BNODE, N);
    int nloc = top - nb0;

    for (int i = t; i <= nloc; i += 256) rbase[i] = rowstart[nb0 + i];
    for (int i = t; i < nloc;  i += 256) lcur[i] = 0;
    __syncthreads();

    int s0 = rbase[0], s1 = rbase[nloc];
    int cnt = s1 - s0;

    if (cnt <= CAP) {
        for (int i = s0 + t; i < s1; i += 256) {
            int p = ebuf[i];
            int n = p >> 17;
            int slot = (rbase[n] - s0) + atomicAdd(&lcur[n], 1);
            sorted[slot] = p & 0x1FFFF;
        }
        __syncthreads();
        for (int i = t; i < cnt; i += 256) esrc[s0 + i] = sorted[i];  // coalesced
    } else {
        for (int i = s0 + t; i < s1; i += 256) {
            int p = ebuf[i];
            int n = p >> 17;
            int slot = rbase[n] + atomicAdd(&lcur[n], 1);
            esrc[slot] = p & 0x1FFFF;
        }
    }
}

// ---------------- gather: CSR mean-aggregate (round-3 proven) ----------------
__global__ __launch_bounds__(256) void gather_kernel(
    const float* __restrict__ x,
    const int*   __restrict__ rowstart,
    const int*   __restrict__ esrc,
    float* __restrict__ mean,
    int N)
{
    int tid  = threadIdx.x;
    int lane = tid & 63;
    int g    = lane >> 4;
    int l4   = (lane & 15) * 4;
    int node = blockIdx.x * 4 + (tid >> 6);
    if (node >= N) return;
    int s0 = rowstart[node], s1 = rowstart[node + 1];

    float4 a0 = make_float4(0.f, 0.f, 0.f, 0.f);
    float4 a1 = make_float4(0.f, 0.f, 0.f, 0.f);
    int e = s0 + g;
    for (; e + 4 < s1; e += 8) {
        int sA = esrc[e];
        int sB = esrc[e + 4];
        float4 va = *(const float4*)&x[(size_t)sA * 64 + l4];
        float4 vb = *(const float4*)&x[(size_t)sB * 64 + l4];
        a0.x += va.x; a0.y += va.y; a0.z += va.z; a0.w += va.w;
        a1.x += vb.x; a1.y += vb.y; a1.z += vb.z; a1.w += vb.w;
    }
    if (e < s1) {
        float4 va = *(const float4*)&x[(size_t)esrc[e] * 64 + l4];
        a0.x += va.x; a0.y += va.y; a0.z += va.z; a0.w += va.w;
    }
    a0.x += a1.x; a0.y += a1.y; a0.z += a1.z; a0.w += a1.w;

    a0.x += __shfl_xor(a0.x, 32); a0.y += __shfl_xor(a0.y, 32);
    a0.z += __shfl_xor(a0.z, 32); a0.w += __shfl_xor(a0.w, 32);
    a0.x += __shfl_xor(a0.x, 16); a0.y += __shfl_xor(a0.y, 16);
    a0.z += __shfl_xor(a0.z, 16); a0.w += __shfl_xor(a0.w, 16);

    if (g == 0) {
        float inv = 1.0f / fmaxf((float)(s1 - s0), 1.0f);
        float4 r = make_float4(a0.x * inv, a0.y * inv, a0.z * inv, a0.w * inv);
        *(float4*)&mean[(size_t)node * 64 + l4] = r;
    }
}

// ---------------- MLP + LayerNorm + ELU ----------------
// Round-10 structure (thread=node, wave=j-quarter, s_load weights via
// readfirstlane'd `part`), c-loop kept ROLLED (#pragma unroll 1: round 11's
// full unroll needed 2048 live weights -> SGPR pressure demoted s_load to
// per-lane VMEM, 5x VALU instructions, 128us). Fix for round 10's exposed
// per-chunk VMEM latency: manual 1-deep software pipeline — issue chunk c+1's
// four float4 loads BEFORE computing chunk c; the compiler's use-point vmcnt
// wait then lands after 512 cycles of fmacs, hiding the latency. +16 VGPR.
__global__ __launch_bounds__(256, 4) void mlp_kernel(
    const float* __restrict__ x,
    const float* mean,              // aliases out - no restrict
    const float* __restrict__ Wl,
    const float* __restrict__ Wr,
    const float* __restrict__ bias,
    const float* __restrict__ gamma,
    const float* __restrict__ beta,
    float* out,
    int N)
{
    __shared__ float sp[4][64];
    __shared__ float sq[4][64];

    int lane = threadIdx.x & 63;
    int part = __builtin_amdgcn_readfirstlane(threadIdx.x >> 6); // SGPR-pinned
    int nbase = blockIdx.x * 64;
    int node  = nbase + lane;
    bool act  = node < N;
    size_t row = (size_t)(act ? node : 0) * 64;

    const float* Wlp = Wl + part * 16 * 64;   // provably uniform -> s_load
    const float* Wrp = Wr + part * 16 * 64;

    float acc[16];
    #pragma unroll
    for (int j = 0; j < 16; ++j) acc[j] = bias[part * 16 + j];

    // prime the pipeline: chunk 0 inputs
    float4 ma = *(const float4*)&mean[row];
    float4 mb = *(const float4*)&mean[row + 4];
    float4 xa = *(const float4*)&x[row];
    float4 xb = *(const float4*)&x[row + 4];

    #pragma unroll 1
    for (int c = 0; c < 8; ++c) {
        // issue next chunk's loads (clamped addr on last iter; redundant 64B)
        int cn = (c < 7) ? c + 1 : 7;
        float4 nma = *(const float4*)&mean[row + cn * 8];
        float4 nmb = *(const float4*)&mean[row + cn * 8 + 4];
        float4 nxa = *(const float4*)&x[row + cn * 8];
        float4 nxb = *(const float4*)&x[row + cn * 8 + 4];

        float vm[8] = {ma.x, ma.y, ma.z, ma.w, mb.x, mb.y, mb.z, mb.w};
        float vx[8] = {xa.x, xa.y, xa.z, xa.w, xb.x, xb.y, xb.z, xb.w};
        const float* wlc = Wlp + c * 8;       // uniform base -> s_load
        const float* wrc = Wrp + c * 8;
        #pragma unroll
        for (int j = 0; j < 16; ++j) {
            #pragma unroll
            for (int d = 0; d < 8; ++d) {
                acc[j] += wlc[j * 64 + d] * vm[d]
                        + wrc[j * 64 + d] * vx[d];
            }
        }

        ma = nma; mb = nmb; xa = nxa; xb = nxb;
    }

    float s0 = 0.f, s1 = 0.f, q0 = 0.f, q1 = 0.f;
    #pragma unroll
    for (int j = 0; j < 8; ++j) {
        s0 += acc[j];     q0 += acc[j] * acc[j];
        s1 += acc[j + 8]; q1 += acc[j + 8] * acc[j + 8];
    }
    sp[part][lane] = s0 + s1;
    sq[part][lane] = q0 + q1;
    __syncthreads();

    float st = (sp[0][lane] + sp[1][lane]) + (sp[2][lane] + sp[3][lane]);
    float qt = (sq[0][lane] + sq[1][lane]) + (sq[2][lane] + sq[3][lane]);
    float mu  = st * (1.0f / 64.0f);
    float var = qt * (1.0f / 64.0f) - mu * mu;
    float r   = rsqrtf(var + LN_EPS);

    if (act) {
        #pragma unroll
        for (int cc = 0; cc < 4; ++cc) {
            float4 g4 = *(const float4*)&gamma[part * 16 + cc * 4];
            float4 b4 = *(const float4*)&beta[part * 16 + cc * 4];
            float4 o;
            o.x = (acc[cc*4+0] - mu) * r * g4.x + b4.x;
            o.y = (acc[cc*4+1] - mu) * r * g4.y + b4.y;
            o.z = (acc[cc*4+2] - mu) * r * g4.z + b4.z;
            o.w = (acc[cc*4+3] - mu) * r * g4.w + b4.w;
            o.x = o.x > 0.f ? o.x : __expf(o.x) - 1.0f;
            o.y = o.y > 0.f ? o.y : __expf(o.y) - 1.0f;
            o.z = o.z > 0.f ? o.z : __expf(o.z) - 1.0f;
            o.w = o.w > 0.f ? o.w : __expf(o.w) - 1.0f;
            *(float4*)&out[(size_t)node * 64 + part * 16 + cc * 4] = o;
        }
    }
}

extern "C" void kernel_launch(void* const* d_in, const int* in_sizes, int n_in,
                              void* d_out, int out_size, void* d_ws, size_t ws_size,
                              hipStream_t stream) {
    const float* x     = (const float*)d_in[0];
    const int*   ei    = (const int*)  d_in[1];
    const float* Wl    = (const float*)d_in[2];
    const float* Wr    = (const float*)d_in[3];
    const float* bias  = (const float*)d_in[4];
    const float* gamma = (const float*)d_in[5];
    const float* beta  = (const float*)d_in[6];

    int N  = in_sizes[0] / 64;
    int E  = in_sizes[1] / 2;
    int NB = (N + BNODE - 1) >> BSH;       // 782 buckets

    int* deg      = (int*)d_ws;            // N
    int* rowstart = deg + N;               // N+1
    int* tilesum  = rowstart + (N + 1);    // <=64
    int* gcursor  = tilesum + 64;          // NB
    int* ebuf     = gcursor + NB;          // E (packed src | dstlocal<<17)
    int* esrc     = ebuf + E;              // E (CSR-ordered src)
    float* mean   = (float*)d_out;         // N*64; mlp reads its rows pre-barrier

    hipMemsetAsync(deg, 0, (size_t)N * sizeof(int), stream);

    hist_kernel<<<(E + 255) / 256, 256, 0, stream>>>(ei, deg, E);

    int T = (N + 2047) / 2048;
    scan1_kernel<<<T, 256, 0, stream>>>(deg, rowstart, tilesum, N);
    scan2_kernel<<<1, 64, 0, stream>>>(tilesum, T);
    scan3_kernel<<<(N + 255) / 256, 256, 0, stream>>>(rowstart, tilesum, gcursor, N, E);

    bucket_scatter_kernel<<<(E + EPB - 1) / EPB, 256, 0, stream>>>(ei, gcursor,
                                                                   ebuf, E, NB);

    csrsort_kernel<<<NB, 256, 0, stream>>>(rowstart, ebuf, esrc, N);

    gather_kernel<<<(N + 3) / 4, 256, 0, stream>>>(x, rowstart, esrc, mean, N);

    mlp_kernel<<<(N + 63) / 64, 256, 0, stream>>>(x, mean, Wl, Wr, bias, gamma, beta,
                                                  (float*)d_out, N);
}